// Round 1
// baseline (29.059 us; speedup 1.0000x reference)
//
#include <hip/hip_runtime.h>
#include <math.h>

#define HW (1024*1024)
#define BATCH 16

// Kernel 1: compute per-(batch,channel) complex affine params.
// mod[b, j] = (x@W_in.T + b_in)[b,j] * tanh((x@W_gate.T + b_gate)[b,j]),
// j = kind*4 + c*2 + r, kind in {lerp, bias, scale}.
// l = mod[b,0,c,:] + (0.5, 0);  bias = mod[b,1,c,:];  s = mod[b,2,c,:] + (1, 0)
// Folded: z_final = z1*s*(1-l) + z2*s*l + bias  =>  A = s*(1-l), B = s*l.
// par layout: [16][2][6] = {Ar, Ai, Br, Bi, biasr, biasi}
__global__ __launch_bounds__(192) void params_kernel(
    const float* __restrict__ x,       // [16][64]
    const float* __restrict__ W_in,    // [12][64]
    const float* __restrict__ b_in,    // [12]
    const float* __restrict__ W_gate,  // [12][64]
    const float* __restrict__ b_gate,  // [12]
    float* __restrict__ par)           // [16][2][6]
{
    __shared__ float smod[BATCH][12];
    int t = threadIdx.x;
    int b = t / 12, j = t % 12;
    if (b < BATCH) {
        float xt = b_in[j], xg = b_gate[j];
        for (int k = 0; k < 64; ++k) {
            float xv = x[b * 64 + k];
            xt = fmaf(xv, W_in[j * 64 + k], xt);
            xg = fmaf(xv, W_gate[j * 64 + k], xg);
        }
        smod[b][j] = xt * tanhf(xg);
    }
    __syncthreads();
    if (t < 32) {
        int bb = t >> 1, c = t & 1;
        float l0 = smod[bb][0 * 4 + c * 2 + 0] + 0.5f;
        float l1 = smod[bb][0 * 4 + c * 2 + 1];
        float br = smod[bb][1 * 4 + c * 2 + 0];
        float bi = smod[bb][1 * 4 + c * 2 + 1];
        float s0 = smod[bb][2 * 4 + c * 2 + 0] + 1.0f;
        float s1 = smod[bb][2 * 4 + c * 2 + 1];
        // (1 - l) = (1 - l0, -l1)
        float omr = 1.0f - l0, omi = -l1;
        float Ar = s0 * omr - s1 * omi;
        float Ai = s0 * omi + s1 * omr;
        float Br = s0 * l0 - s1 * l1;
        float Bi = s0 * l1 + s1 * l0;
        float* p = par + (bb * 2 + c) * 6;
        p[0] = Ar; p[1] = Ai; p[2] = Br; p[3] = Bi; p[4] = br; p[5] = bi;
    }
}

// Kernel 2: streaming transform. Each thread owns 4 consecutive hw positions,
// loads 8 weight floats per (j,c) combo (2x float4), loops over 16 batches.
// weights flat layout: [j][c][HW][2]  (j = lerp endpoint, c = channel, r = re/im)
__global__ __launch_bounds__(256) void main_kernel(
    const float* __restrict__ wts,   // [2][2][HW][2]
    const float* __restrict__ par,   // [16][2][6]
    float* __restrict__ out)         // [16][HW]
{
    __shared__ float sp[192];
    int t = threadIdx.x;
    if (t < 192) sp[t] = par[t];
    __syncthreads();

    int idx = blockIdx.x * 256 + t;          // 0 .. HW/4 - 1
    const float4* w4 = (const float4*)wts;   // [jc][HW/2] float4s

    // Wv[jc][half]: jc = j*2 + c; covers 4 hw positions (8 floats) per jc.
    float4 Wv[4][2];
#pragma unroll
    for (int jc = 0; jc < 4; ++jc) {
        Wv[jc][0] = w4[jc * (HW / 2) + idx * 2 + 0];
        Wv[jc][1] = w4[jc * (HW / 2) + idx * 2 + 1];
    }
    const float* w00 = (const float*)Wv[0];  // j=0, c=0
    const float* w01 = (const float*)Wv[1];  // j=0, c=1
    const float* w10 = (const float*)Wv[2];  // j=1, c=0
    const float* w11 = (const float*)Wv[3];  // j=1, c=1

    float4* out4 = (float4*)out;
#pragma unroll
    for (int b = 0; b < BATCH; ++b) {
        const float* p0 = &sp[(b * 2 + 0) * 6];
        const float* p1 = &sp[(b * 2 + 1) * 6];
        float A0r = p0[0], A0i = p0[1], B0r = p0[2], B0i = p0[3], c0r = p0[4], c0i = p0[5];
        float A1r = p1[0], A1i = p1[1], B1r = p1[2], B1i = p1[3], c1r = p1[4], c1i = p1[5];
        float4 o;
        float* op = (float*)&o;
#pragma unroll
        for (int p = 0; p < 4; ++p) {
            float a0r = w00[p * 2], a0i = w00[p * 2 + 1];
            float b0r = w10[p * 2], b0i = w10[p * 2 + 1];
            float a1r = w01[p * 2], a1i = w01[p * 2 + 1];
            float b1r = w11[p * 2], b1i = w11[p * 2 + 1];
            // z0 = A0*w00 + B0*w10 + bias0 (complex)
            float z0r = c0r + A0r * a0r - A0i * a0i + B0r * b0r - B0i * b0i;
            float z0i = c0i + A0r * a0i + A0i * a0r + B0r * b0i + B0i * b0r;
            // z1 = A1*w01 + B1*w11 + bias1
            float z1r = c1r + A1r * a1r - A1i * a1i + B1r * b1r - B1i * b1i;
            float z1i = c1i + A1r * a1i + A1i * a1r + B1r * b1i + B1i * b1r;
            float rs = rsqrtf(z1r * z1r + z1i * z1i + 1e-12f);
            op[p] = (z0r * z1r + z0i * z1i) * rs;
        }
        out4[b * (HW / 4) + idx] = o;
    }
}

extern "C" void kernel_launch(void* const* d_in, const int* in_sizes, int n_in,
                              void* d_out, int out_size, void* d_ws, size_t ws_size,
                              hipStream_t stream) {
    const float* x      = (const float*)d_in[0];
    const float* W_in   = (const float*)d_in[1];
    const float* b_in   = (const float*)d_in[2];
    const float* W_gate = (const float*)d_in[3];
    const float* b_gate = (const float*)d_in[4];
    const float* wts    = (const float*)d_in[5];
    float* out = (float*)d_out;
    float* par = (float*)d_ws;

    params_kernel<<<1, 192, 0, stream>>>(x, W_in, b_in, W_gate, b_gate, par);
    main_kernel<<<1024, 256, 0, stream>>>(wts, par, out);
}